// Round 3
// baseline (494.585 us; speedup 1.0000x reference)
//
#include <hip/hip_runtime.h>

typedef unsigned short u16;
typedef unsigned int   u32;
typedef __attribute__((ext_vector_type(4))) float f32x4;
typedef __attribute__((ext_vector_type(4))) u32   u32x4;
typedef __attribute__((ext_vector_type(8))) __bf16 bf16x8;

#define S_LEN 2048
#define EMB   2048
#define NH    16
#define HD    128
#define NBH   32
#define MTOT  4096
#define NUP   120   // strict-upper 128x128 tiles per bh
#define NBMIN (NBH * NUP + 512)

__device__ __forceinline__ u16 f2bf(float f) {
    u32 u = __float_as_uint(f);
    return (u16)((u + 0x7FFFu + ((u >> 16) & 1u)) >> 16);
}
__device__ __forceinline__ float bf2f(u16 v) {
    return __uint_as_float(((u32)v) << 16);
}
__device__ __forceinline__ bf16x8 ld_frag(const u16* p) {
    return __builtin_bit_cast(bf16x8, *(const u32x4*)p);
}
__device__ __forceinline__ void gld_lds16(const void* g, void* l) {
    __builtin_amdgcn_global_load_lds(
        (__attribute__((address_space(1))) void*)(g),
        (__attribute__((address_space(3))) void*)(l), 16, 0, 0);
}

// ============================================================================
// cast X fp32 -> bf16
// ============================================================================
__global__ __launch_bounds__(256) void cast_x_kernel(
    const float* __restrict__ X, u16* __restrict__ Xb)
{
    const size_t i = ((size_t)blockIdx.x * 256 + threadIdx.x) * 8;
    float4 a = *(const float4*)&X[i];
    float4 b = *(const float4*)&X[i + 4];
    u32x4 o;
    o.x = (u32)f2bf(a.x) | ((u32)f2bf(a.y) << 16);
    o.y = (u32)f2bf(a.z) | ((u32)f2bf(a.w) << 16);
    o.z = (u32)f2bf(b.x) | ((u32)f2bf(b.y) << 16);
    o.w = (u32)f2bf(b.z) | ((u32)f2bf(b.w) << 16);
    *(u32x4*)&Xb[i] = o;
}

// ============================================================================
// transpose-cast weights: W [K][N] fp32 -> Wt [N][K] bf16
// ============================================================================
__global__ __launch_bounds__(256) void transpose_cast_w_kernel(
    const float* __restrict__ W0, const float* __restrict__ W1,
    const float* __restrict__ W2, const float* __restrict__ W3,
    u16* __restrict__ T0, u16* __restrict__ T1,
    u16* __restrict__ T2, u16* __restrict__ T3)
{
    __shared__ float Ls[64][68];
    const int t = threadIdx.x;
    const int n0 = blockIdx.x * 64, k0 = blockIdx.y * 64;
    const int z = blockIdx.z;
    const float* __restrict__ W = (z == 0) ? W0 : (z == 1) ? W1 : (z == 2) ? W2 : W3;
    u16* __restrict__ T = (z == 0) ? T0 : (z == 1) ? T1 : (z == 2) ? T2 : T3;

#pragma unroll
    for (int p = 0; p < 4; ++p) {
        const int r = (t >> 4) + 16 * p;
        const int c = (t & 15) * 4;
        *(float4*)&Ls[r][c] = *(const float4*)&W[(size_t)(k0 + r) * EMB + n0 + c];
    }
    __syncthreads();
    const int nl = t >> 2, q = t & 3;
    u32 pk[8];
#pragma unroll
    for (int j = 0; j < 8; ++j) {
        u16 lo = f2bf(Ls[q * 16 + 2 * j][nl]);
        u16 hi = f2bf(Ls[q * 16 + 2 * j + 1][nl]);
        pk[j] = (u32)lo | ((u32)hi << 16);
    }
    u32x4 o0 = {pk[0], pk[1], pk[2], pk[3]};
    u32x4 o1 = {pk[4], pk[5], pk[6], pk[7]};
    u16* dst = &T[(size_t)(n0 + nl) * EMB + k0 + q * 16];
    *(u32x4*)&dst[0] = o0;
    *(u32x4*)&dst[8] = o1;
}

// ============================================================================
// transpose V bf16 [bh][s][d] -> Vt [bh][d][s]
// ============================================================================
__global__ __launch_bounds__(256) void transpose_v_kernel(
    const u16* __restrict__ V, u16* __restrict__ Vt)
{
    __shared__ u16 Ls[64][72];
    const int t = threadIdx.x;
    const int s0 = blockIdx.x * 64, d0 = blockIdx.y * 64, bh = blockIdx.z;
    const u16* __restrict__ src0 = V + ((size_t)bh * S_LEN) * HD;
    {
        const int r = t >> 2, c0 = (t & 3) * 16;
        const u16* src = &src0[(size_t)(s0 + r) * HD + d0 + c0];
        *(u32x4*)&Ls[r][c0]     = *(const u32x4*)&src[0];
        *(u32x4*)&Ls[r][c0 + 8] = *(const u32x4*)&src[8];
    }
    __syncthreads();
    const int dl = t >> 2, q = t & 3;
    u32 pk[8];
#pragma unroll
    for (int j = 0; j < 8; ++j) {
        u16 lo = Ls[q * 16 + 2 * j][dl];
        u16 hi = Ls[q * 16 + 2 * j + 1][dl];
        pk[j] = (u32)lo | ((u32)hi << 16);
    }
    u32x4 o0 = {pk[0], pk[1], pk[2], pk[3]};
    u32x4 o1 = {pk[4], pk[5], pk[6], pk[7]};
    u16* dst = &Vt[((size_t)bh * HD + d0 + dl) * S_LEN + s0 + q * 16];
    *(u32x4*)&dst[0] = o0;
    *(u32x4*)&dst[8] = o1;
}

// ============================================================================
// bf16 MFMA GEMM (m97 pattern), qkv variant
// ============================================================================
__global__ __launch_bounds__(256) void gemm_qkv_mfma(
    const u16* __restrict__ Xb,
    const u16* __restrict__ Wtq, const u16* __restrict__ Wtk,
    const u16* __restrict__ Wtv,
    u16* __restrict__ Qo, u16* __restrict__ Ko, u16* __restrict__ Vo)
{
    __shared__ __attribute__((aligned(16))) u16 As[128 * 32];
    __shared__ __attribute__((aligned(16))) u16 Bs[128 * 32];
    const int t = threadIdx.x;
    const int w = t >> 6, lane = t & 63;
    const int wy = w >> 1, wx = w & 1;
    const int n0 = blockIdx.x * 128, m0 = blockIdx.y * 128;
    const int z = blockIdx.z;
    const u16* __restrict__ Wt = (z == 0) ? Wtq : (z == 1) ? Wtk : Wtv;
    u16* __restrict__ O = (z == 0) ? Qo : (z == 1) ? Ko : Vo;

    const int srow = lane >> 2, scol = (lane & 3) * 8;
    const u16* Ag = &Xb[(size_t)(m0 + w * 32 + srow) * EMB + scol];
    const u16* Bg = &Wt[(size_t)(n0 + w * 32 + srow) * EMB + scol];
    u16* Al0 = &As[(w * 32) * 32];
    u16* Al1 = &As[(w * 32 + 16) * 32];
    u16* Bl0 = &Bs[(w * 32) * 32];
    u16* Bl1 = &Bs[(w * 32 + 16) * 32];

    const int fm = lane & 15, fk = (lane >> 4) * 8;
    f32x4 acc[4][4];
#pragma unroll
    for (int i = 0; i < 4; ++i)
#pragma unroll
        for (int j = 0; j < 4; ++j) acc[i][j] = (f32x4)0.0f;

    for (int k0 = 0; k0 < EMB; k0 += 32) {
        __syncthreads();
        gld_lds16(Ag + k0, Al0);
        gld_lds16(Ag + 16 * EMB + k0, Al1);
        gld_lds16(Bg + k0, Bl0);
        gld_lds16(Bg + 16 * EMB + k0, Bl1);
        __syncthreads();
        bf16x8 af[4], bfr[4];
#pragma unroll
        for (int mi = 0; mi < 4; ++mi)
            af[mi] = ld_frag(&As[(64 * wy + 16 * mi + fm) * 32 + fk]);
#pragma unroll
        for (int ni = 0; ni < 4; ++ni)
            bfr[ni] = ld_frag(&Bs[(64 * wx + 16 * ni + fm) * 32 + fk]);
#pragma unroll
        for (int mi = 0; mi < 4; ++mi)
#pragma unroll
            for (int ni = 0; ni < 4; ++ni)
                acc[mi][ni] = __builtin_amdgcn_mfma_f32_16x16x32_bf16(
                    af[mi], bfr[ni], acc[mi][ni], 0, 0, 0);
    }

    const int q4 = (lane >> 4) * 4;
#pragma unroll
    for (int mi = 0; mi < 4; ++mi)
#pragma unroll
        for (int ni = 0; ni < 4; ++ni) {
            const int n = n0 + 64 * wx + 16 * ni + (lane & 15);
            const int h = n >> 7, d = n & 127;
#pragma unroll
            for (int r = 0; r < 4; ++r) {
                const int m = m0 + 64 * wy + 16 * mi + q4 + r;
                const int bb = m >> 11, s = m & 2047;
                O[(((size_t)(bb * NH + h) * S_LEN) + s) * HD + d] = f2bf(acc[mi][ni][r]);
            }
        }
}

__global__ __launch_bounds__(256) void gemm_out_mfma(
    const u16* __restrict__ Ab, const u16* __restrict__ Wto,
    const float* __restrict__ bias, float* __restrict__ Out)
{
    __shared__ __attribute__((aligned(16))) u16 As[128 * 32];
    __shared__ __attribute__((aligned(16))) u16 Bs[128 * 32];
    const int t = threadIdx.x;
    const int w = t >> 6, lane = t & 63;
    const int wy = w >> 1, wx = w & 1;
    const int n0 = blockIdx.x * 128, m0 = blockIdx.y * 128;

    const int srow = lane >> 2, scol = (lane & 3) * 8;
    const u16* Ag = &Ab[(size_t)(m0 + w * 32 + srow) * EMB + scol];
    const u16* Bg = &Wto[(size_t)(n0 + w * 32 + srow) * EMB + scol];
    u16* Al0 = &As[(w * 32) * 32];
    u16* Al1 = &As[(w * 32 + 16) * 32];
    u16* Bl0 = &Bs[(w * 32) * 32];
    u16* Bl1 = &Bs[(w * 32 + 16) * 32];

    const int fm = lane & 15, fk = (lane >> 4) * 8;
    f32x4 acc[4][4];
#pragma unroll
    for (int i = 0; i < 4; ++i)
#pragma unroll
        for (int j = 0; j < 4; ++j) acc[i][j] = (f32x4)0.0f;

    for (int k0 = 0; k0 < EMB; k0 += 32) {
        __syncthreads();
        gld_lds16(Ag + k0, Al0);
        gld_lds16(Ag + 16 * EMB + k0, Al1);
        gld_lds16(Bg + k0, Bl0);
        gld_lds16(Bg + 16 * EMB + k0, Bl1);
        __syncthreads();
        bf16x8 af[4], bfr[4];
#pragma unroll
        for (int mi = 0; mi < 4; ++mi)
            af[mi] = ld_frag(&As[(64 * wy + 16 * mi + fm) * 32 + fk]);
#pragma unroll
        for (int ni = 0; ni < 4; ++ni)
            bfr[ni] = ld_frag(&Bs[(64 * wx + 16 * ni + fm) * 32 + fk]);
#pragma unroll
        for (int mi = 0; mi < 4; ++mi)
#pragma unroll
            for (int ni = 0; ni < 4; ++ni)
                acc[mi][ni] = __builtin_amdgcn_mfma_f32_16x16x32_bf16(
                    af[mi], bfr[ni], acc[mi][ni], 0, 0, 0);
    }

    const int q4 = (lane >> 4) * 4;
#pragma unroll
    for (int mi = 0; mi < 4; ++mi)
#pragma unroll
        for (int ni = 0; ni < 4; ++ni) {
            const int n = n0 + 64 * wx + 16 * ni + (lane & 15);
            const float bv = bias[n];
#pragma unroll
            for (int r = 0; r < 4; ++r) {
                const int m = m0 + 64 * wy + 16 * mi + q4 + r;
                Out[(size_t)m * EMB + n] = acc[mi][ni][r] + bv;
            }
        }
}

// ============================================================================
// Min over strict-upper tiles only (kt > qt): 120 tiles per bh.
// ============================================================================
__global__ __launch_bounds__(256) void qk_upper_min(
    const u16* __restrict__ Q, const u16* __restrict__ K,
    float* __restrict__ blockmin)
{
    __shared__ __attribute__((aligned(16))) u16 As[128 * 32];
    __shared__ __attribute__((aligned(16))) u16 Bs[128 * 32];
    __shared__ float sm[256];
    const int t = threadIdx.x;
    const int w = t >> 6, lane = t & 63;
    const int wy = w >> 1, wx = w & 1;
    // decode linear upper-tile index -> (qt, kt) with kt > qt
    int u = blockIdx.x, qt = 0, cnt = 15;
    while (u >= cnt) { u -= cnt; ++qt; cnt = 15 - qt; }
    const int kt = qt + 1 + u;
    const int bh = blockIdx.y;

    const int srow = lane >> 2, scol = (lane & 3) * 8;
    const u16* Ag = &Q[((size_t)bh * S_LEN + qt * 128 + w * 32 + srow) * HD + scol];
    const u16* Bg = &K[((size_t)bh * S_LEN + kt * 128 + w * 32 + srow) * HD + scol];
    u16* Al0 = &As[(w * 32) * 32];
    u16* Al1 = &As[(w * 32 + 16) * 32];
    u16* Bl0 = &Bs[(w * 32) * 32];
    u16* Bl1 = &Bs[(w * 32 + 16) * 32];

    const int fm = lane & 15, fk = (lane >> 4) * 8;
    f32x4 acc[4][4];
#pragma unroll
    for (int i = 0; i < 4; ++i)
#pragma unroll
        for (int j = 0; j < 4; ++j) acc[i][j] = (f32x4)0.0f;

    for (int k0 = 0; k0 < HD; k0 += 32) {
        __syncthreads();
        gld_lds16(Ag + k0, Al0);
        gld_lds16(Ag + 16 * HD + k0, Al1);
        gld_lds16(Bg + k0, Bl0);
        gld_lds16(Bg + 16 * HD + k0, Bl1);
        __syncthreads();
        bf16x8 af[4], bfr[4];
#pragma unroll
        for (int mi = 0; mi < 4; ++mi)
            af[mi] = ld_frag(&As[(64 * wy + 16 * mi + fm) * 32 + fk]);
#pragma unroll
        for (int ni = 0; ni < 4; ++ni)
            bfr[ni] = ld_frag(&Bs[(64 * wx + 16 * ni + fm) * 32 + fk]);
#pragma unroll
        for (int mi = 0; mi < 4; ++mi)
#pragma unroll
            for (int ni = 0; ni < 4; ++ni)
                acc[mi][ni] = __builtin_amdgcn_mfma_f32_16x16x32_bf16(
                    af[mi], bfr[ni], acc[mi][ni], 0, 0, 0);
    }

    float mn = acc[0][0][0];
#pragma unroll
    for (int mi = 0; mi < 4; ++mi)
#pragma unroll
        for (int ni = 0; ni < 4; ++ni)
#pragma unroll
            for (int r = 0; r < 4; ++r) mn = fminf(mn, acc[mi][ni][r]);
    sm[t] = mn;
    __syncthreads();
    for (int sft = 128; sft > 0; sft >>= 1) {
        if (t < sft) sm[t] = fminf(sm[t], sm[t + sft]);
        __syncthreads();
    }
    if (t == 0) blockmin[(size_t)bh * NUP + blockIdx.x] = sm[0];
}

__global__ __launch_bounds__(256) void reduce_min_kernel(
    const float* __restrict__ bm, float* __restrict__ minval)
{
    __shared__ float sm[256];
    const int t = threadIdx.x;
    float m = 3.0e38f;
    for (int i = t; i < NBMIN; i += 256) m = fminf(m, bm[i]);
    sm[t] = m;
    __syncthreads();
    for (int sft = 128; sft > 0; sft >>= 1) {
        if (t < sft) sm[t] = fminf(sm[t], sm[t + sft]);
        __syncthreads();
    }
    if (t == 0) minval[0] = sm[0];
}

// ============================================================================
// V suffix sums (bf16 in, fp32 out)
// ============================================================================
__global__ __launch_bounds__(128) void vchunk_sum_kernel(
    const u16* __restrict__ V, float* __restrict__ csum)
{
    const int chunk = blockIdx.x, bh = blockIdx.y, d = threadIdx.x;
    const u16* vb = V + ((size_t)bh * S_LEN + chunk * 64) * HD + d;
    float s = 0.0f;
    for (int r = 0; r < 64; ++r) s += bf2f(vb[(size_t)r * HD]);
    csum[((size_t)bh * 32 + chunk) * HD + d] = s;
}

__global__ __launch_bounds__(128) void vchunk_suffix_kernel(
    const float* __restrict__ csum, float* __restrict__ csuf)
{
    const int bh = blockIdx.x, d = threadIdx.x;
    float run = 0.0f;
    for (int c = 31; c >= 0; --c) {
        const size_t idx = ((size_t)bh * 32 + c) * HD + d;
        csuf[idx] = run;
        run += csum[idx];
    }
}

__global__ __launch_bounds__(128) void vsuffix_kernel(
    const u16* __restrict__ V, const float* __restrict__ csuf,
    float* __restrict__ vsuf)
{
    const int chunk = blockIdx.x, bh = blockIdx.y, d = threadIdx.x;
    float run = csuf[((size_t)bh * 32 + chunk) * HD + d];
    const size_t base = ((size_t)bh * S_LEN + chunk * 64) * HD + d;
    for (int r = 63; r >= 0; --r) {
        vsuf[base + (size_t)r * HD] = run;
        run += bf2f(V[base + (size_t)r * HD]);
    }
}

// ============================================================================
// Balanced flash attention: block = (pair p, kt-parity h, bh).
// Processes q-tiles {p, 15-p}; for each, tiles jt<=qt with jt&1==h
// (8 or 9 tile-steps per block, exactly balanced).
// Emits RAW partials (no mask correction): bf16 oacc into pacc[h],
// fp32 row denominators into den_p[h], block min over all computed
// (pre-mask) scores into blockmin. finalize_kernel combines.
// ============================================================================
__global__ __launch_bounds__(256) void attn_mfma(
    const u16* __restrict__ Q, const u16* __restrict__ K,
    const u16* __restrict__ Vt,
    u16* __restrict__ pacc0, u16* __restrict__ pacc1,
    float* __restrict__ den_p, float* __restrict__ blockmin)
{
    __shared__ __attribute__((aligned(16))) u16 Qs[128 * 136];
    __shared__ __attribute__((aligned(16))) u16 Ps[128 * 136];
    __shared__ __attribute__((aligned(16))) u16 Cs[128 * 32];
    __shared__ float den_l[2][128];
    __shared__ float smn[256];

    const int t = threadIdx.x;
    const int w = t >> 6, lane = t & 63;
    const int wy = w >> 1, wx = w & 1;
    const int pp = blockIdx.x >> 1, hpar = blockIdx.x & 1;
    const int bh = blockIdx.y;
    const int b = bh >> 4, h = bh & 15;

    const u16* __restrict__ Kg  = K + (size_t)bh * S_LEN * HD;
    const u16* __restrict__ Vtg = Vt + (size_t)bh * HD * S_LEN;
    u16* __restrict__ pacc = hpar ? pacc1 : pacc0;

    const int srow = lane >> 2, scol = (lane & 3) * 8;
    const int fm = lane & 15, fk = (lane >> 4) * 8;
    const int q4 = (lane >> 4) * 4;

    float mn = 3.0e38f;

    for (int pass = 0; pass < 2; ++pass) {
        const int qt = pass ? (15 - pp) : pp;
        const int i0 = qt * 128;
        const u16* __restrict__ Qg = Q + ((size_t)bh * S_LEN + i0) * HD;

        __syncthreads();  // prior-pass LDS consumers done before Qs restage
        {
            const int r = t >> 1, ch = (t & 1) * 64;
            const u16* src = &Qg[(size_t)r * HD + ch];
            u16* dst = &Qs[r * 136 + ch];
#pragma unroll
            for (int j = 0; j < 8; ++j)
                *(u32x4*)&dst[j * 8] = *(const u32x4*)&src[j * 8];
        }

        f32x4 oacc[4][4];
#pragma unroll
        for (int i = 0; i < 4; ++i)
#pragma unroll
            for (int j = 0; j < 4; ++j) oacc[i][j] = (f32x4)0.0f;
        float den[4][4] = {};

        for (int jt = hpar; jt <= qt; jt += 2) {
            const int j0 = jt * 128;
            // ---- S = Q K^T ----
            f32x4 sacc[4][4];
#pragma unroll
            for (int i = 0; i < 4; ++i)
#pragma unroll
                for (int j = 0; j < 4; ++j) sacc[i][j] = (f32x4)0.0f;
            for (int dk = 0; dk < 4; ++dk) {
                __syncthreads();
                {
                    const u16* g = &Kg[(size_t)(j0 + w * 32 + srow) * HD + dk * 32 + scol];
                    gld_lds16(g, &Cs[(w * 32) * 32]);
                    gld_lds16(g + 16 * HD, &Cs[(w * 32 + 16) * 32]);
                }
                __syncthreads();
                bf16x8 af[4], bfr[4];
#pragma unroll
                for (int mi = 0; mi < 4; ++mi)
                    af[mi] = ld_frag(&Qs[(64 * wy + 16 * mi + fm) * 136 + dk * 32 + fk]);
#pragma unroll
                for (int ni = 0; ni < 4; ++ni)
                    bfr[ni] = ld_frag(&Cs[(64 * wx + 16 * ni + fm) * 32 + fk]);
#pragma unroll
                for (int mi = 0; mi < 4; ++mi)
#pragma unroll
                    for (int ni = 0; ni < 4; ++ni)
                        sacc[mi][ni] = __builtin_amdgcn_mfma_f32_16x16x32_bf16(
                            af[mi], bfr[ni], sacc[mi][ni], 0, 0, 0);
            }
            // ---- min (pre-mask) + exp epilogue -> Ps, den ----
            const bool dg = (jt == qt);
#pragma unroll
            for (int mi = 0; mi < 4; ++mi) {
                const int rbase = 64 * wy + 16 * mi + q4;
#pragma unroll
                for (int ni = 0; ni < 4; ++ni) {
                    const int cl = 64 * wx + 16 * ni + (lane & 15);
                    const int jg = j0 + cl;
#pragma unroll
                    for (int r = 0; r < 4; ++r) {
                        const float s = sacc[mi][ni][r];
                        mn = fminf(mn, s);
                        float e = __expf(s);
                        if (dg && jg > i0 + rbase + r) e = 0.0f;
                        den[mi][r] += e;
                        Ps[(rbase + r) * 136 + cl] = f2bf(e);
                    }
                }
            }
            __syncthreads();  // scores done -> Cs reusable; Ps visible

            // ---- O += P V ----
            for (int sk = 0; sk < 4; ++sk) {
                if (sk) __syncthreads();
                {
                    const u16* g = &Vtg[(size_t)(w * 32 + srow) * S_LEN + j0 + sk * 32 + scol];
                    gld_lds16(g, &Cs[(w * 32) * 32]);
                    gld_lds16(g + 16 * S_LEN, &Cs[(w * 32 + 16) * 32]);
                }
                __syncthreads();
                bf16x8 pa[4], pb[4];
#pragma unroll
                for (int mi = 0; mi < 4; ++mi)
                    pa[mi] = ld_frag(&Ps[(64 * wy + 16 * mi + fm) * 136 + sk * 32 + fk]);
#pragma unroll
                for (int ni = 0; ni < 4; ++ni)
                    pb[ni] = ld_frag(&Cs[(64 * wx + 16 * ni + fm) * 32 + fk]);
#pragma unroll
                for (int mi = 0; mi < 4; ++mi)
#pragma unroll
                    for (int ni = 0; ni < 4; ++ni)
                        oacc[mi][ni] = __builtin_amdgcn_mfma_f32_16x16x32_bf16(
                            pa[mi], pb[ni], oacc[mi][ni], 0, 0, 0);
            }
        }

        // ---- row-sum reduce den across the 16 col-lanes of each quad ----
#pragma unroll
        for (int mi = 0; mi < 4; ++mi)
#pragma unroll
            for (int r = 0; r < 4; ++r) {
                float v = den[mi][r];
                v += __shfl_xor(v, 1, 64);
                v += __shfl_xor(v, 2, 64);
                v += __shfl_xor(v, 4, 64);
                v += __shfl_xor(v, 8, 64);
                den[mi][r] = v;
            }
        __syncthreads();
        if ((lane & 15) == 0) {
#pragma unroll
            for (int mi = 0; mi < 4; ++mi)
#pragma unroll
                for (int r = 0; r < 4; ++r)
                    den_l[wx][64 * wy + 16 * mi + q4 + r] = den[mi][r];
        }
        __syncthreads();
        if (t < 128)
            den_p[((size_t)hpar * NBH + bh) * S_LEN + i0 + t] =
                den_l[0][t] + den_l[1][t];

        // ---- raw partial write (bf16) ----
#pragma unroll
        for (int mi = 0; mi < 4; ++mi)
#pragma unroll
            for (int ni = 0; ni < 4; ++ni) {
                const int d = 64 * wx + 16 * ni + (lane & 15);
#pragma unroll
                for (int r = 0; r < 4; ++r) {
                    const int row = 64 * wy + 16 * mi + q4 + r;
                    pacc[((size_t)b * S_LEN + i0 + row) * EMB + h * HD + d] =
                        f2bf(oacc[mi][ni][r]);
                }
            }
    }

    // ---- block min ----
    __syncthreads();
    smn[t] = mn;
    __syncthreads();
    for (int sft = 128; sft > 0; sft >>= 1) {
        if (t < sft) smn[t] = fminf(smn[t], smn[t + sft]);
        __syncthreads();
    }
    if (t == 0) blockmin[blockIdx.y * 16 + blockIdx.x] = smn[0];
}

// ============================================================================
// finalize: outm = (p0 + p1 + em*vsuf) / (den0 + den1 + (S-1-s)*em), in place.
// ============================================================================
__global__ __launch_bounds__(256) void finalize_kernel(
    u16* __restrict__ outm, const u16* __restrict__ pacc1,
    const float* __restrict__ vsuf, const float* __restrict__ den_p,
    const float* __restrict__ minval)
{
    const size_t i = ((size_t)blockIdx.x * 256 + threadIdx.x) * 8;
    const int e = (int)(i & (EMB - 1));
    const int m = (int)(i / EMB);
    const int b = m >> 11, s = m & 2047;
    const int hh = e >> 7, d = e & 127;
    const int bh = b * NH + hh;
    const float em = __expf(minval[0]);
    const float den = den_p[(size_t)bh * S_LEN + s]
                    + den_p[((size_t)NBH + bh) * S_LEN + s]
                    + (float)(S_LEN - 1 - s) * em;
    const float inv = 1.0f / den;
    u32x4 a = *(const u32x4*)&outm[i];
    u32x4 c = *(const u32x4*)&pacc1[i];
    const u16* pa = (const u16*)&a;
    const u16* pc = (const u16*)&c;
    const float* vs = &vsuf[((size_t)bh * S_LEN + s) * HD + d];
    u16 ov[8];
#pragma unroll
    for (int j = 0; j < 8; ++j) {
        const float v = bf2f(pa[j]) + bf2f(pc[j]) + em * vs[j];
        ov[j] = f2bf(v * inv);
    }
    *(u32x4*)&outm[i] = *(const u32x4*)ov;
}

// ============================================================================
// Launch
// ============================================================================
extern "C" void kernel_launch(void* const* d_in, const int* in_sizes, int n_in,
                              void* d_out, int out_size, void* d_ws, size_t ws_size,
                              hipStream_t stream)
{
    (void)in_sizes; (void)n_in; (void)out_size; (void)ws_size;
    const float* hs = (const float*)d_in[0];
    const float* wq = (const float*)d_in[1];
    const float* wk = (const float*)d_in[2];
    const float* wv = (const float*)d_in[3];
    const float* wo = (const float*)d_in[4];
    const float* bo = (const float*)d_in[5];
    float* out = (float*)d_out;

    char* p = (char*)d_ws;
    const size_t TS = (size_t)NBH * S_LEN * HD;  // 8388608
    u16* Xb   = (u16*)p; p += (size_t)MTOT * EMB * 2;   // dead after gemm_qkv
    u16* Wtq  = (u16*)p; p += (size_t)EMB * EMB * 2;
    u16* Wtk  = (u16*)p; p += (size_t)EMB * EMB * 2;
    u16* Wtv  = (u16*)p; p += (size_t)EMB * EMB * 2;
    u16* Wto  = (u16*)p; p += (size_t)EMB * EMB * 2;
    u16* Qb   = (u16*)p; p += TS * 2;
    u16* Kb   = (u16*)p; p += TS * 2;
    u16* Vb   = (u16*)p; p += TS * 2;
    u16* Vtb  = (u16*)p; p += TS * 2;
    u16* outm = (u16*)p; p += (size_t)MTOT * EMB * 2;   // pacc0, then final merged
    float* vsuf     = (float*)p; p += TS * 4;
    float* csum     = (float*)p; p += (size_t)NBH * 32 * HD * 4;
    float* csuf     = (float*)p; p += (size_t)NBH * 32 * HD * 4;
    float* blockmin = (float*)p; p += 8192 * 4;
    float* minval   = (float*)p; p += 64;
    float* den_p    = (float*)p; p += (size_t)2 * NBH * S_LEN * 4;
    u16* pacc1 = Xb;  // overlay: Xb is dead once gemm_qkv has run

    cast_x_kernel<<<4096, 256, 0, stream>>>(hs, Xb);
    transpose_cast_w_kernel<<<dim3(32, 32, 4), 256, 0, stream>>>(
        wq, wk, wv, wo, Wtq, Wtk, Wtv, Wto);

    gemm_qkv_mfma<<<dim3(EMB / 128, MTOT / 128, 3), 256, 0, stream>>>(
        Xb, Wtq, Wtk, Wtv, Qb, Kb, Vb);

    transpose_v_kernel<<<dim3(32, 2, NBH), 256, 0, stream>>>(Vb, Vtb);
    vchunk_sum_kernel<<<dim3(32, NBH), 128, 0, stream>>>(Vb, csum);
    vchunk_suffix_kernel<<<NBH, 128, 0, stream>>>(csum, csuf);
    vsuffix_kernel<<<dim3(32, NBH), 128, 0, stream>>>(Vb, csuf, vsuf);

    qk_upper_min<<<dim3(NUP, NBH), 256, 0, stream>>>(Qb, Kb, blockmin);

    attn_mfma<<<dim3(16, NBH), 256, 0, stream>>>(
        Qb, Kb, Vtb, outm, pacc1, den_p, blockmin + (size_t)NBH * NUP);

    reduce_min_kernel<<<1, 256, 0, stream>>>(blockmin, minval);

    finalize_kernel<<<(MTOT * EMB / 8) / 256, 256, 0, stream>>>(
        outm, pacc1, vsuf, den_p, minval);

    gemm_out_mfma<<<dim3(EMB / 128, MTOT / 128), 256, 0, stream>>>(
        outm, Wto, bo, out);
}

// Round 4
// 462.749 us; speedup vs baseline: 1.0688x; 1.0688x over previous
//
#include <hip/hip_runtime.h>

typedef unsigned short u16;
typedef unsigned int   u32;
typedef __attribute__((ext_vector_type(4))) float f32x4;
typedef __attribute__((ext_vector_type(4))) u32   u32x4;
typedef __attribute__((ext_vector_type(8))) __bf16 bf16x8;

#define S_LEN 2048
#define EMB   2048
#define NH    16
#define HD    128
#define NBH   32
#define MTOT  4096
#define NBMIN 512

__device__ __forceinline__ u16 f2bf(float f) {
    u32 u = __float_as_uint(f);
    return (u16)((u + 0x7FFFu + ((u >> 16) & 1u)) >> 16);
}
__device__ __forceinline__ float bf2f(u16 v) {
    return __uint_as_float(((u32)v) << 16);
}
__device__ __forceinline__ bf16x8 ld_frag(const u16* p) {
    return __builtin_bit_cast(bf16x8, *(const u32x4*)p);
}
__device__ __forceinline__ void gld_lds16(const void* g, void* l) {
    __builtin_amdgcn_global_load_lds(
        (__attribute__((address_space(1))) void*)(g),
        (__attribute__((address_space(3))) void*)(l), 16, 0, 0);
}

// ============================================================================
// cast X fp32 -> bf16
// ============================================================================
__global__ __launch_bounds__(256) void cast_x_kernel(
    const float* __restrict__ X, u16* __restrict__ Xb)
{
    const size_t i = ((size_t)blockIdx.x * 256 + threadIdx.x) * 8;
    float4 a = *(const float4*)&X[i];
    float4 b = *(const float4*)&X[i + 4];
    u32x4 o;
    o.x = (u32)f2bf(a.x) | ((u32)f2bf(a.y) << 16);
    o.y = (u32)f2bf(a.z) | ((u32)f2bf(a.w) << 16);
    o.z = (u32)f2bf(b.x) | ((u32)f2bf(b.y) << 16);
    o.w = (u32)f2bf(b.z) | ((u32)f2bf(b.w) << 16);
    *(u32x4*)&Xb[i] = o;
}

// ============================================================================
// transpose-cast weights: W [K][N] fp32 -> Wt [N][K] bf16
// ============================================================================
__global__ __launch_bounds__(256) void transpose_cast_w_kernel(
    const float* __restrict__ W0, const float* __restrict__ W1,
    const float* __restrict__ W2, const float* __restrict__ W3,
    u16* __restrict__ T0, u16* __restrict__ T1,
    u16* __restrict__ T2, u16* __restrict__ T3)
{
    __shared__ float Ls[64][68];
    const int t = threadIdx.x;
    const int n0 = blockIdx.x * 64, k0 = blockIdx.y * 64;
    const int z = blockIdx.z;
    const float* __restrict__ W = (z == 0) ? W0 : (z == 1) ? W1 : (z == 2) ? W2 : W3;
    u16* __restrict__ T = (z == 0) ? T0 : (z == 1) ? T1 : (z == 2) ? T2 : T3;

#pragma unroll
    for (int p = 0; p < 4; ++p) {
        const int r = (t >> 4) + 16 * p;
        const int c = (t & 15) * 4;
        *(float4*)&Ls[r][c] = *(const float4*)&W[(size_t)(k0 + r) * EMB + n0 + c];
    }
    __syncthreads();
    const int nl = t >> 2, q = t & 3;
    u32 pk[8];
#pragma unroll
    for (int j = 0; j < 8; ++j) {
        u16 lo = f2bf(Ls[q * 16 + 2 * j][nl]);
        u16 hi = f2bf(Ls[q * 16 + 2 * j + 1][nl]);
        pk[j] = (u32)lo | ((u32)hi << 16);
    }
    u32x4 o0 = {pk[0], pk[1], pk[2], pk[3]};
    u32x4 o1 = {pk[4], pk[5], pk[6], pk[7]};
    u16* dst = &T[(size_t)(n0 + nl) * EMB + k0 + q * 16];
    *(u32x4*)&dst[0] = o0;
    *(u32x4*)&dst[8] = o1;
}

// ============================================================================
// transpose V bf16 [bh][s][d] -> Vt [bh][d][s]
// ============================================================================
__global__ __launch_bounds__(256) void transpose_v_kernel(
    const u16* __restrict__ V, u16* __restrict__ Vt)
{
    __shared__ u16 Ls[64][72];
    const int t = threadIdx.x;
    const int s0 = blockIdx.x * 64, d0 = blockIdx.y * 64, bh = blockIdx.z;
    const u16* __restrict__ src0 = V + ((size_t)bh * S_LEN) * HD;
    {
        const int r = t >> 2, c0 = (t & 3) * 16;
        const u16* src = &src0[(size_t)(s0 + r) * HD + d0 + c0];
        *(u32x4*)&Ls[r][c0]     = *(const u32x4*)&src[0];
        *(u32x4*)&Ls[r][c0 + 8] = *(const u32x4*)&src[8];
    }
    __syncthreads();
    const int dl = t >> 2, q = t & 3;
    u32 pk[8];
#pragma unroll
    for (int j = 0; j < 8; ++j) {
        u16 lo = Ls[q * 16 + 2 * j][dl];
        u16 hi = Ls[q * 16 + 2 * j + 1][dl];
        pk[j] = (u32)lo | ((u32)hi << 16);
    }
    u32x4 o0 = {pk[0], pk[1], pk[2], pk[3]};
    u32x4 o1 = {pk[4], pk[5], pk[6], pk[7]};
    u16* dst = &Vt[((size_t)bh * HD + d0 + dl) * S_LEN + s0 + q * 16];
    *(u32x4*)&dst[0] = o0;
    *(u32x4*)&dst[8] = o1;
}

// ============================================================================
// bf16 MFMA GEMM (m97 pattern), qkv variant
// ============================================================================
__global__ __launch_bounds__(256) void gemm_qkv_mfma(
    const u16* __restrict__ Xb,
    const u16* __restrict__ Wtq, const u16* __restrict__ Wtk,
    const u16* __restrict__ Wtv,
    u16* __restrict__ Qo, u16* __restrict__ Ko, u16* __restrict__ Vo)
{
    __shared__ __attribute__((aligned(16))) u16 As[128 * 32];
    __shared__ __attribute__((aligned(16))) u16 Bs[128 * 32];
    const int t = threadIdx.x;
    const int w = t >> 6, lane = t & 63;
    const int wy = w >> 1, wx = w & 1;
    const int n0 = blockIdx.x * 128, m0 = blockIdx.y * 128;
    const int z = blockIdx.z;
    const u16* __restrict__ Wt = (z == 0) ? Wtq : (z == 1) ? Wtk : Wtv;
    u16* __restrict__ O = (z == 0) ? Qo : (z == 1) ? Ko : Vo;

    const int srow = lane >> 2, scol = (lane & 3) * 8;
    const u16* Ag = &Xb[(size_t)(m0 + w * 32 + srow) * EMB + scol];
    const u16* Bg = &Wt[(size_t)(n0 + w * 32 + srow) * EMB + scol];
    u16* Al0 = &As[(w * 32) * 32];
    u16* Al1 = &As[(w * 32 + 16) * 32];
    u16* Bl0 = &Bs[(w * 32) * 32];
    u16* Bl1 = &Bs[(w * 32 + 16) * 32];

    const int fm = lane & 15, fk = (lane >> 4) * 8;
    f32x4 acc[4][4];
#pragma unroll
    for (int i = 0; i < 4; ++i)
#pragma unroll
        for (int j = 0; j < 4; ++j) acc[i][j] = (f32x4)0.0f;

    for (int k0 = 0; k0 < EMB; k0 += 32) {
        __syncthreads();
        gld_lds16(Ag + k0, Al0);
        gld_lds16(Ag + 16 * EMB + k0, Al1);
        gld_lds16(Bg + k0, Bl0);
        gld_lds16(Bg + 16 * EMB + k0, Bl1);
        __syncthreads();
        bf16x8 af[4], bfr[4];
#pragma unroll
        for (int mi = 0; mi < 4; ++mi)
            af[mi] = ld_frag(&As[(64 * wy + 16 * mi + fm) * 32 + fk]);
#pragma unroll
        for (int ni = 0; ni < 4; ++ni)
            bfr[ni] = ld_frag(&Bs[(64 * wx + 16 * ni + fm) * 32 + fk]);
#pragma unroll
        for (int mi = 0; mi < 4; ++mi)
#pragma unroll
            for (int ni = 0; ni < 4; ++ni)
                acc[mi][ni] = __builtin_amdgcn_mfma_f32_16x16x32_bf16(
                    af[mi], bfr[ni], acc[mi][ni], 0, 0, 0);
    }

    const int q4 = (lane >> 4) * 4;
#pragma unroll
    for (int mi = 0; mi < 4; ++mi)
#pragma unroll
        for (int ni = 0; ni < 4; ++ni) {
            const int n = n0 + 64 * wx + 16 * ni + (lane & 15);
            const int h = n >> 7, d = n & 127;
#pragma unroll
            for (int r = 0; r < 4; ++r) {
                const int m = m0 + 64 * wy + 16 * mi + q4 + r;
                const int bb = m >> 11, s = m & 2047;
                O[(((size_t)(bb * NH + h) * S_LEN) + s) * HD + d] = f2bf(acc[mi][ni][r]);
            }
        }
}

__global__ __launch_bounds__(256) void gemm_out_mfma(
    const u16* __restrict__ Ab, const u16* __restrict__ Wto,
    const float* __restrict__ bias, float* __restrict__ Out)
{
    __shared__ __attribute__((aligned(16))) u16 As[128 * 32];
    __shared__ __attribute__((aligned(16))) u16 Bs[128 * 32];
    const int t = threadIdx.x;
    const int w = t >> 6, lane = t & 63;
    const int wy = w >> 1, wx = w & 1;
    const int n0 = blockIdx.x * 128, m0 = blockIdx.y * 128;

    const int srow = lane >> 2, scol = (lane & 3) * 8;
    const u16* Ag = &Ab[(size_t)(m0 + w * 32 + srow) * EMB + scol];
    const u16* Bg = &Wto[(size_t)(n0 + w * 32 + srow) * EMB + scol];
    u16* Al0 = &As[(w * 32) * 32];
    u16* Al1 = &As[(w * 32 + 16) * 32];
    u16* Bl0 = &Bs[(w * 32) * 32];
    u16* Bl1 = &Bs[(w * 32 + 16) * 32];

    const int fm = lane & 15, fk = (lane >> 4) * 8;
    f32x4 acc[4][4];
#pragma unroll
    for (int i = 0; i < 4; ++i)
#pragma unroll
        for (int j = 0; j < 4; ++j) acc[i][j] = (f32x4)0.0f;

    for (int k0 = 0; k0 < EMB; k0 += 32) {
        __syncthreads();
        gld_lds16(Ag + k0, Al0);
        gld_lds16(Ag + 16 * EMB + k0, Al1);
        gld_lds16(Bg + k0, Bl0);
        gld_lds16(Bg + 16 * EMB + k0, Bl1);
        __syncthreads();
        bf16x8 af[4], bfr[4];
#pragma unroll
        for (int mi = 0; mi < 4; ++mi)
            af[mi] = ld_frag(&As[(64 * wy + 16 * mi + fm) * 32 + fk]);
#pragma unroll
        for (int ni = 0; ni < 4; ++ni)
            bfr[ni] = ld_frag(&Bs[(64 * wx + 16 * ni + fm) * 32 + fk]);
#pragma unroll
        for (int mi = 0; mi < 4; ++mi)
#pragma unroll
            for (int ni = 0; ni < 4; ++ni)
                acc[mi][ni] = __builtin_amdgcn_mfma_f32_16x16x32_bf16(
                    af[mi], bfr[ni], acc[mi][ni], 0, 0, 0);
    }

    const int q4 = (lane >> 4) * 4;
#pragma unroll
    for (int mi = 0; mi < 4; ++mi)
#pragma unroll
        for (int ni = 0; ni < 4; ++ni) {
            const int n = n0 + 64 * wx + 16 * ni + (lane & 15);
            const float bv = bias[n];
#pragma unroll
            for (int r = 0; r < 4; ++r) {
                const int m = m0 + 64 * wy + 16 * mi + q4 + r;
                Out[(size_t)m * EMB + n] = acc[mi][ni][r] + bv;
            }
        }
}

__global__ __launch_bounds__(256) void reduce_min_kernel(
    const float* __restrict__ bm, float* __restrict__ minval)
{
    __shared__ float sm[256];
    const int t = threadIdx.x;
    float m = 3.0e38f;
    for (int i = t; i < NBMIN; i += 256) m = fminf(m, bm[i]);
    sm[t] = m;
    __syncthreads();
    for (int sft = 128; sft > 0; sft >>= 1) {
        if (t < sft) sm[t] = fminf(sm[t], sm[t + sft]);
        __syncthreads();
    }
    if (t == 0) minval[0] = sm[0];
}

// ============================================================================
// V suffix sums (bf16 in, bf16 out; fp32 carry)
// ============================================================================
__global__ __launch_bounds__(128) void vchunk_sum_kernel(
    const u16* __restrict__ V, float* __restrict__ csum)
{
    const int chunk = blockIdx.x, bh = blockIdx.y, d = threadIdx.x;
    const u16* vb = V + ((size_t)bh * S_LEN + chunk * 64) * HD + d;
    float s = 0.0f;
    for (int r = 0; r < 64; ++r) s += bf2f(vb[(size_t)r * HD]);
    csum[((size_t)bh * 32 + chunk) * HD + d] = s;
}

__global__ __launch_bounds__(128) void vchunk_suffix_kernel(
    const float* __restrict__ csum, float* __restrict__ csuf)
{
    const int bh = blockIdx.x, d = threadIdx.x;
    float run = 0.0f;
    for (int c = 31; c >= 0; --c) {
        const size_t idx = ((size_t)bh * 32 + c) * HD + d;
        csuf[idx] = run;
        run += csum[idx];
    }
}

__global__ __launch_bounds__(128) void vsuffix_kernel(
    const u16* __restrict__ V, const float* __restrict__ csuf,
    u16* __restrict__ vsuf)
{
    const int chunk = blockIdx.x, bh = blockIdx.y, d = threadIdx.x;
    float run = csuf[((size_t)bh * 32 + chunk) * HD + d];
    const size_t base = ((size_t)bh * S_LEN + chunk * 64) * HD + d;
    for (int r = 63; r >= 0; --r) {
        vsuf[base + (size_t)r * HD] = f2bf(run);
        run += bf2f(V[base + (size_t)r * HD]);
    }
}

// ============================================================================
// Pipelined flash attention + full-square min, bf16 MFMA.
// Block = (pair pp, parity hpar, bh); passes qt = pp then 15-pp.
// Per pass: Q fragments held in REGISTERS (no Qs LDS); for jt in
// {hpar, hpar+2, ..., 15}: QK (4 chunks) always (pre-mask min over every
// tile -> covers the whole S x S square across blocks); if jt <= qt also
// exp->Ps and PV (4 chunks). K/V 8KB chunks ping-pong through Cs[2] with
// the prefetch for chunk i+1 issued right AFTER the barrier publishing
// chunk i, so each barrier's vmcnt drain waits on a DMA issued one full
// MFMA-phase earlier (1 barrier per chunk instead of 2, drains hidden).
// Raw bf16 partials (parity split) + fp32 row dens out; finalize combines.
// ============================================================================
__global__ __launch_bounds__(256) void attn_mfma(
    const u16* __restrict__ Q, const u16* __restrict__ K,
    const u16* __restrict__ Vt,
    u16* __restrict__ pacc0, u16* __restrict__ pacc1,
    float* __restrict__ den_p, float* __restrict__ blockmin)
{
    __shared__ __attribute__((aligned(16))) u16 Ps[128 * 136];
    __shared__ __attribute__((aligned(16))) u16 Cs[2][128 * 32];
    __shared__ float den_l[2][128];
    __shared__ float smn[256];

    const int t = threadIdx.x;
    const int w = t >> 6, lane = t & 63;
    const int wy = w >> 1, wx = w & 1;
    const int pp = blockIdx.x >> 1, hpar = blockIdx.x & 1;
    const int bh = blockIdx.y;
    const int b = bh >> 4, h = bh & 15;

    const u16* __restrict__ Kg  = K + (size_t)bh * S_LEN * HD;
    const u16* __restrict__ Vtg = Vt + (size_t)bh * HD * S_LEN;
    u16* __restrict__ pacc = hpar ? pacc1 : pacc0;

    const int srow = lane >> 2, scol = (lane & 3) * 8;
    const int fm = lane & 15, fk = (lane >> 4) * 8;
    const int q4 = (lane >> 4) * 4;

    // wave-uniform LDS staging bases (lane i lands at base + i*16)
    u16* cs0a = &Cs[0][(w * 32) * 32];
    u16* cs0b = &Cs[0][(w * 32 + 16) * 32];
    u16* cs1a = &Cs[1][(w * 32) * 32];
    u16* cs1b = &Cs[1][(w * 32 + 16) * 32];

    float mn = 3.0e38f;
    int c = 0;

    // prologue: first K chunk of pass 0
    {
        const u16* g = &Kg[(size_t)(hpar * 128 + w * 32 + srow) * HD + scol];
        gld_lds16(g, cs0a);
        gld_lds16(g + 16 * HD, cs0b);
    }
    __syncthreads();

    for (int pass = 0; pass < 2; ++pass) {
        const int qt = pass ? (15 - pp) : pp;
        const int i0 = qt * 128;
        const u16* __restrict__ Qg = Q + ((size_t)bh * S_LEN + i0) * HD;

        // Q fragments -> registers (once per pass)
        bf16x8 af[4][4];
#pragma unroll
        for (int mi = 0; mi < 4; ++mi)
#pragma unroll
            for (int dk = 0; dk < 4; ++dk)
                af[mi][dk] = ld_frag(
                    &Qg[(size_t)(64 * wy + 16 * mi + fm) * HD + dk * 32 + fk]);

        f32x4 oacc[4][4];
#pragma unroll
        for (int i = 0; i < 4; ++i)
#pragma unroll
            for (int j = 0; j < 4; ++j) oacc[i][j] = (f32x4)0.0f;
        float den[4][4] = {};

        for (int ji = 0; ji < 8; ++ji) {
            const int jt = hpar + 2 * ji;
            const int j0 = jt * 128;
            const bool causal = (jt <= qt);
            const bool last_step = (ji == 7);
            const bool have_next = (!last_step) || (pass == 0);
            const int nj0 = last_step ? hpar * 128 : (jt + 2) * 128;

            // ---- QK: 4 chunks ----
            f32x4 sacc[4][4];
#pragma unroll
            for (int i = 0; i < 4; ++i)
#pragma unroll
                for (int j = 0; j < 4; ++j) sacc[i][j] = (f32x4)0.0f;

            for (int dk = 0; dk < 4; ++dk) {
                // prefetch next chunk into the other buffer
                u16* na = c ? cs0a : cs1a;
                u16* nb = c ? cs0b : cs1b;
                if (dk < 3) {
                    const u16* g = &Kg[(size_t)(j0 + w * 32 + srow) * HD
                                       + (dk + 1) * 32 + scol];
                    gld_lds16(g, na);
                    gld_lds16(g + 16 * HD, nb);
                } else if (causal) {
                    const u16* g = &Vtg[(size_t)(w * 32 + srow) * S_LEN + j0 + scol];
                    gld_lds16(g, na);
                    gld_lds16(g + 16 * S_LEN, nb);
                } else if (have_next) {
                    const u16* g = &Kg[(size_t)(nj0 + w * 32 + srow) * HD + scol];
                    gld_lds16(g, na);
                    gld_lds16(g + 16 * HD, nb);
                }
                // consume current buffer
                bf16x8 bfr[4];
#pragma unroll
                for (int ni = 0; ni < 4; ++ni)
                    bfr[ni] = ld_frag(&Cs[c][(64 * wx + 16 * ni + fm) * 32 + fk]);
#pragma unroll
                for (int mi = 0; mi < 4; ++mi)
#pragma unroll
                    for (int ni = 0; ni < 4; ++ni)
                        sacc[mi][ni] = __builtin_amdgcn_mfma_f32_16x16x32_bf16(
                            af[mi][dk], bfr[ni], sacc[mi][ni], 0, 0, 0);

                if (dk == 3) {
                    // epilogue overlaps the in-flight DMA
                    if (causal) {
                        const bool dg = (jt == qt);
#pragma unroll
                        for (int mi = 0; mi < 4; ++mi) {
                            const int rbase = 64 * wy + 16 * mi + q4;
#pragma unroll
                            for (int ni = 0; ni < 4; ++ni) {
                                const int cl = 64 * wx + 16 * ni + fm;
                                const int jg = j0 + cl;
#pragma unroll
                                for (int r = 0; r < 4; ++r) {
                                    const float s = sacc[mi][ni][r];
                                    mn = fminf(mn, s);
                                    float e = __expf(s);
                                    if (dg && jg > i0 + rbase + r) e = 0.0f;
                                    den[mi][r] += e;
                                    Ps[(rbase + r) * 136 + cl] = f2bf(e);
                                }
                            }
                        }
                    } else {
#pragma unroll
                        for (int mi = 0; mi < 4; ++mi)
#pragma unroll
                            for (int ni = 0; ni < 4; ++ni)
#pragma unroll
                                for (int r = 0; r < 4; ++r)
                                    mn = fminf(mn, sacc[mi][ni][r]);
                    }
                }
                __syncthreads();
                c ^= 1;
            }

            // ---- PV: 4 chunks (causal only) ----
            if (causal) {
                for (int sk = 0; sk < 4; ++sk) {
                    u16* na = c ? cs0a : cs1a;
                    u16* nb = c ? cs0b : cs1b;
                    if (sk < 3) {
                        const u16* g = &Vtg[(size_t)(w * 32 + srow) * S_LEN
                                            + j0 + (sk + 1) * 32 + scol];
                        gld_lds16(g, na);
                        gld_lds16(g + 16 * S_LEN, nb);
                    } else if (have_next) {
                        const u16* g = &Kg[(size_t)(nj0 + w * 32 + srow) * HD + scol];
                        gld_lds16(g, na);
                        gld_lds16(g + 16 * HD, nb);
                    }
                    bf16x8 pa[4], pb[4];
#pragma unroll
                    for (int mi = 0; mi < 4; ++mi)
                        pa[mi] = ld_frag(&Ps[(64 * wy + 16 * mi + fm) * 136
                                             + sk * 32 + fk]);
#pragma unroll
                    for (int ni = 0; ni < 4; ++ni)
                        pb[ni] = ld_frag(&Cs[c][(64 * wx + 16 * ni + fm) * 32 + fk]);
#pragma unroll
                    for (int mi = 0; mi < 4; ++mi)
#pragma unroll
                        for (int ni = 0; ni < 4; ++ni)
                            oacc[mi][ni] = __builtin_amdgcn_mfma_f32_16x16x32_bf16(
                                pa[mi], pb[ni], oacc[mi][ni], 0, 0, 0);
                    __syncthreads();
                    c ^= 1;
                }
            }
        }

        // ---- pass epilogue: den reduce + raw partial write ----
#pragma unroll
        for (int mi = 0; mi < 4; ++mi)
#pragma unroll
            for (int r = 0; r < 4; ++r) {
                float v = den[mi][r];
                v += __shfl_xor(v, 1, 64);
                v += __shfl_xor(v, 2, 64);
                v += __shfl_xor(v, 4, 64);
                v += __shfl_xor(v, 8, 64);
                den[mi][r] = v;
            }
        __syncthreads();
        if ((lane & 15) == 0) {
#pragma unroll
            for (int mi = 0; mi < 4; ++mi)
#pragma unroll
                for (int r = 0; r < 4; ++r)
                    den_l[wx][64 * wy + 16 * mi + q4 + r] = den[mi][r];
        }
        __syncthreads();
        if (t < 128)
            den_p[((size_t)hpar * NBH + bh) * S_LEN + i0 + t] =
                den_l[0][t] + den_l[1][t];

#pragma unroll
        for (int mi = 0; mi < 4; ++mi)
#pragma unroll
            for (int ni = 0; ni < 4; ++ni) {
                const int d = 64 * wx + 16 * ni + fm;
#pragma unroll
                for (int r = 0; r < 4; ++r) {
                    const int row = 64 * wy + 16 * mi + q4 + r;
                    pacc[((size_t)b * S_LEN + i0 + row) * EMB + h * HD + d] =
                        f2bf(oacc[mi][ni][r]);
                }
            }
        __syncthreads();  // den_l reuse next pass
    }

    // ---- block min ----
    smn[t] = mn;
    __syncthreads();
    for (int sft = 128; sft > 0; sft >>= 1) {
        if (t < sft) smn[t] = fminf(smn[t], smn[t + sft]);
        __syncthreads();
    }
    if (t == 0) blockmin[blockIdx.y * 16 + blockIdx.x] = smn[0];
}

// ============================================================================
// finalize: outm = (p0 + p1 + em*vsuf) / (den0 + den1 + (S-1-s)*em), in place.
// ============================================================================
__global__ __launch_bounds__(256) void finalize_kernel(
    u16* __restrict__ outm, const u16* __restrict__ pacc1,
    const u16* __restrict__ vsuf, const float* __restrict__ den_p,
    const float* __restrict__ minval)
{
    const size_t i = ((size_t)blockIdx.x * 256 + threadIdx.x) * 8;
    const int e = (int)(i & (EMB - 1));
    const int m = (int)(i / EMB);
    const int b = m >> 11, s = m & 2047;
    const int hh = e >> 7, d = e & 127;
    const int bh = b * NH + hh;
    const float em = __expf(minval[0]);
    const float den = den_p[(size_t)bh * S_LEN + s]
                    + den_p[((size_t)NBH + bh) * S_LEN + s]
                    + (float)(S_LEN - 1 - s) * em;
    const float inv = 1.0f / den;
    u32x4 a = *(const u32x4*)&outm[i];
    u32x4 cc = *(const u32x4*)&pacc1[i];
    u32x4 vv = *(const u32x4*)&vsuf[((size_t)bh * S_LEN + s) * HD + d];
    const u16* pa = (const u16*)&a;
    const u16* pc = (const u16*)&cc;
    const u16* pv = (const u16*)&vv;
    u16 ov[8];
#pragma unroll
    for (int j = 0; j < 8; ++j) {
        const float v = bf2f(pa[j]) + bf2f(pc[j]) + em * bf2f(pv[j]);
        ov[j] = f2bf(v * inv);
    }
    *(u32x4*)&outm[i] = *(const u32x4*)ov;
}

// ============================================================================
// Launch
// ============================================================================
extern "C" void kernel_launch(void* const* d_in, const int* in_sizes, int n_in,
                              void* d_out, int out_size, void* d_ws, size_t ws_size,
                              hipStream_t stream)
{
    (void)in_sizes; (void)n_in; (void)out_size; (void)ws_size;
    const float* hs = (const float*)d_in[0];
    const float* wq = (const float*)d_in[1];
    const float* wk = (const float*)d_in[2];
    const float* wv = (const float*)d_in[3];
    const float* wo = (const float*)d_in[4];
    const float* bo = (const float*)d_in[5];
    float* out = (float*)d_out;

    char* p = (char*)d_ws;
    const size_t TS = (size_t)NBH * S_LEN * HD;  // 8388608
    u16* Xb   = (u16*)p; p += (size_t)MTOT * EMB * 2;   // dead after gemm_qkv
    u16* Wtq  = (u16*)p; p += (size_t)EMB * EMB * 2;
    u16* Wtk  = (u16*)p; p += (size_t)EMB * EMB * 2;
    u16* Wtv  = (u16*)p; p += (size_t)EMB * EMB * 2;
    u16* Wto  = (u16*)p; p += (size_t)EMB * EMB * 2;
    u16* Qb   = (u16*)p; p += TS * 2;
    u16* Kb   = (u16*)p; p += TS * 2;
    u16* Vb   = (u16*)p; p += TS * 2;
    u16* Vtb  = (u16*)p; p += TS * 2;
    u16* outm = (u16*)p; p += (size_t)MTOT * EMB * 2;   // pacc0, then merged
    u16* vsuf = (u16*)p; p += TS * 2;
    float* csum     = (float*)p; p += (size_t)NBH * 32 * HD * 4;
    float* csuf     = (float*)p; p += (size_t)NBH * 32 * HD * 4;
    float* blockmin = (float*)p; p += 1024 * 4;
    float* minval   = (float*)p; p += 64;
    float* den_p    = (float*)p; p += (size_t)2 * NBH * S_LEN * 4;
    u16* pacc1 = Xb;  // overlay: Xb dead once gemm_qkv has run

    cast_x_kernel<<<4096, 256, 0, stream>>>(hs, Xb);
    transpose_cast_w_kernel<<<dim3(32, 32, 4), 256, 0, stream>>>(
        wq, wk, wv, wo, Wtq, Wtk, Wtv, Wto);

    gemm_qkv_mfma<<<dim3(EMB / 128, MTOT / 128, 3), 256, 0, stream>>>(
        Xb, Wtq, Wtk, Wtv, Qb, Kb, Vb);

    transpose_v_kernel<<<dim3(32, 2, NBH), 256, 0, stream>>>(Vb, Vtb);
    vchunk_sum_kernel<<<dim3(32, NBH), 128, 0, stream>>>(Vb, csum);
    vchunk_suffix_kernel<<<NBH, 128, 0, stream>>>(csum, csuf);
    vsuffix_kernel<<<dim3(32, NBH), 128, 0, stream>>>(Vb, csuf, vsuf);

    attn_mfma<<<dim3(16, NBH), 256, 0, stream>>>(
        Qb, Kb, Vtb, outm, pacc1, den_p, blockmin);

    reduce_min_kernel<<<1, 256, 0, stream>>>(blockmin, minval);

    finalize_kernel<<<(MTOT * EMB / 8) / 256, 256, 0, stream>>>(
        outm, pacc1, vsuf, den_p, minval);

    gemm_out_mfma<<<dim3(EMB / 128, MTOT / 128), 256, 0, stream>>>(
        outm, Wto, bo, out);
}